// Round 13
// baseline (28.138 us; speedup 1.0000x reference)
//
#include <hip/hip_runtime.h>
#include <math.h>

#define EPS 1e-6f
#define BN_EPSF 1e-5f
#define PI2F 6.2831853071795864769f
#define INV2PIF 0.15915494309189535f
#define LOG2EF 1.4426950408889634f
#define NBB 4
#define NCC 512
#define NGG 2048
#define OUTC 64
#define NBAS 10

// d_out layout (floats): y_out, n_f, fourier_prior, n_h1, h0_f
#define Y_OFF   0
#define NF_OFF  (NBB*NGG*OUTC)          // 524288
#define FP_OFF  (NF_OFF  + NBB*NGG*9)   // 598016
#define NH1_OFF (FP_OFF  + NBB*NGG*9)   // 671744
#define H0_OFF  (NH1_OFF + NBB*NGG*9)   // 745472

// ws layout (floats)
#define WS_CONV  0                      // NBB*9*NGG = 73728
#define WS_STATS (NBB*9*NGG)            // 9 cps * 512 blocks * {sum,sumsq}

#if defined(__has_builtin)
# if __has_builtin(__builtin_amdgcn_exp2f)
#  define EXP2F(x) __builtin_amdgcn_exp2f(x)
# endif
# if __has_builtin(__builtin_amdgcn_cosf)
#  define COS_REV(r) __builtin_amdgcn_cosf(r)   // cos(2*pi*r), r in [0,1)
# endif
#endif
#ifndef EXP2F
# define EXP2F(x) exp2f(x)
#endif
#ifndef COS_REV
# define COS_REV(r) cosf(PI2F*(r))
#endif

// ---------------------------------------------------------------------------
// K1: RBF (16 own g + 8 halo g) + hw-cos finalize + depthwise conv + BN
// partials — ONE node instead of two (rounds 9-12: all within-kernel levers
// null; totals pinned at 24-25 us => ~5 us/node dispatch overhead dominates).
// 512 blocks (4 b x 128 tiles of 16 g) x 256 threads, p-inner 18 acc
// (spill-free at 256 thr since r9), skewed affine LDS, in-wave shfl folds.
// ---------------------------------------------------------------------------
__global__ __launch_bounds__(256) void k1_fused(
    const float* __restrict__ x_c, const float* __restrict__ y_c,
    const float* __restrict__ x_g, const float* __restrict__ sigma,
    const float* __restrict__ mu, const float* __restrict__ eps1,
    const float* __restrict__ b_u, const float* __restrict__ random_w,
    const float* __restrict__ cw1, const float* __restrict__ cb1,
    const float* __restrict__ cw2, const float* __restrict__ cb2,
    const float* __restrict__ cw3, const float* __restrict__ cb3,
    float* __restrict__ out, float* __restrict__ ws)
{
    const int bid = blockIdx.x;
    const int b = bid >> 7;            // 4 b x 128 tiles of 16 g
    const int gtile = bid & 127;
    const int g0 = gtile * 16;
    const int tid = threadIdx.x;

    __shared__ float cxy[NCC*8 + (NCC/32)*4];  // 16.6 KB skewed (x0,y0,x1,y1,x2,y2,-,-)
    __shared__ float red[4][16][19];           // 4.8 KB own per-wave folded partials
    __shared__ float red2[4][8][19];           // 2.4 KB halo per-wave folded partials
    __shared__ float pre_l[9][24];             // conv input: 0..3 left halo, 4..19 own, 20..23 right
    __shared__ float sw_l[NBAS*3], sb_l[NBAS*3], rw_l[NBAS];

    // ---- stage context set via float4 + small params ----
    const float4* xc4 = (const float4*)(x_c + b*NCC*3);
    const float4* yc4 = (const float4*)(y_c + b*NCC*3);
    for (int i = tid; i < (NCC*3)/4; i += 256) {
        float4 xv = xc4[i];
        float4 yv = yc4[i];
        int f0 = i*4;
        #pragma unroll
        for (int j = 0; j < 4; ++j) {
            int f = f0 + j;
            int n = f/3, c = f - n*3;
            int base = n*8 + ((n>>5)<<2);
            float xs = (j==0)?xv.x:(j==1)?xv.y:(j==2)?xv.z:xv.w;
            float ys = (j==0)?yv.x:(j==1)?yv.y:(j==2)?yv.z:yv.w;
            cxy[base + 2*c]     = xs;
            cxy[base + 2*c + 1] = ys;
        }
    }
    if (tid < NBAS*3) {
        int k = tid/3, p = tid - k*3;
        float wmu  = expf(mu[p]);
        float wstd = 1.0f / (expf(sigma[p]) + EPS);
        sw_l[tid] = wmu + wstd * eps1[(b*NBAS + k)*3 + p];
        sb_l[tid] = PI2F * b_u[(b*NBAS + k)*3 + p];
    }
    if (tid < NBAS) rw_l[tid] = random_w[tid];

    float coef[3];
    #pragma unroll
    for (int p = 0; p < 3; ++p) {
        float s = expf(sigma[p]) + EPS;
        coef[p] = (-0.5f * LOG2EF) / (s*s);   // exp(-0.5 d^2) == exp2(d^2*coef)
    }

    // own: g = tid&15, chunk cA = tid>>4 (16 chunks of 32 ctx)
    const int gA = tid & 15;
    const int cA = tid >> 4;
    const float xgA0 = x_g[(b*NGG + g0 + gA)*3 + 0];
    const float xgA1 = x_g[(b*NGG + g0 + gA)*3 + 1];
    const float xgA2 = x_g[(b*NGG + g0 + gA)*3 + 2];

    // halo: gH = tid&7 (8 pts), cH = tid>>3 (32 chunks of 16 ctx)
    // slots in [g0-4, g0+20): 0..3 left (g0-4..g0-1), 20..23 right (g0+16..g0+19)
    const int gH = tid & 7;
    const int cH = tid >> 3;
    const int gHg = g0 - 4 + ((gH < 4) ? gH : 20 + (gH - 4));
    const int gHc = min(max(gHg, 0), NGG-1);
    const float xgH0 = x_g[(b*NGG + gHc)*3 + 0];
    const float xgH1 = x_g[(b*NGG + gHc)*3 + 1];
    const float xgH2 = x_g[(b*NGG + gHc)*3 + 2];

    __syncthreads();

    const int lane = tid & 63, wv = tid >> 6;

    // ---- A1: own RBF (32 ctx/thread; banks: 4 groups on quads 0/4/8/12) ----
    {
        float h0a[3][3] = {{0}}, h1a[3][3] = {{0}};
        const int fbase = cA * 260;            // cA*32 ctx, skew 4/32pts
        #pragma unroll 4
        for (int i = 0; i < 32; ++i) {
            float4 A = *(const float4*)&cxy[fbase + i*8];
            float4 B = *(const float4*)&cxy[fbase + i*8 + 4];
            float d0 = A.x - xgA0, d1 = A.z - xgA1, d2 = B.x - xgA2;
            float dx2[3] = {d0*d0, d1*d1, d2*d2};
            float yv[3]  = {A.y, A.w, B.y};
            #pragma unroll
            for (int c = 0; c < 3; ++c)
                #pragma unroll
                for (int p = 0; p < 3; ++p) {
                    float w = EXP2F(dx2[c] * coef[p]);
                    h0a[c][p] += w;
                    h1a[c][p] += w * yv[c];
                }
        }
        // fold wave's 4 chunks (lane bits 4,5)
        #pragma unroll
        for (int c = 0; c < 3; ++c)
            #pragma unroll
            for (int p = 0; p < 3; ++p) {
                #pragma unroll
                for (int m = 16; m <= 32; m <<= 1) {
                    h0a[c][p] += __shfl_xor(h0a[c][p], m);
                    h1a[c][p] += __shfl_xor(h1a[c][p], m);
                }
            }
        if (lane < 16) {
            #pragma unroll
            for (int c = 0; c < 3; ++c)
                #pragma unroll
                for (int p = 0; p < 3; ++p) {
                    red[wv][lane][c*3 + p]     = h0a[c][p];
                    red[wv][lane][9 + c*3 + p] = h1a[c][p];
                }
        }
    }

    // ---- A2: halo RBF (16 ctx/thread; banks 2-way = free) ----
    {
        float h0b[3][3] = {{0}}, h1b[3][3] = {{0}};
        const int fbase = cH*128 + ((cH>>1)<<2);
        #pragma unroll 4
        for (int i = 0; i < 16; ++i) {
            float4 A = *(const float4*)&cxy[fbase + i*8];
            float4 B = *(const float4*)&cxy[fbase + i*8 + 4];
            float d0 = A.x - xgH0, d1 = A.z - xgH1, d2 = B.x - xgH2;
            float dx2[3] = {d0*d0, d1*d1, d2*d2};
            float yv[3]  = {A.y, A.w, B.y};
            #pragma unroll
            for (int c = 0; c < 3; ++c)
                #pragma unroll
                for (int p = 0; p < 3; ++p) {
                    float w = EXP2F(dx2[c] * coef[p]);
                    h0b[c][p] += w;
                    h1b[c][p] += w * yv[c];
                }
        }
        // fold wave's 8 chunks (lane bits 3,4,5)
        #pragma unroll
        for (int c = 0; c < 3; ++c)
            #pragma unroll
            for (int p = 0; p < 3; ++p) {
                #pragma unroll
                for (int m = 8; m <= 32; m <<= 1) {
                    h0b[c][p] += __shfl_xor(h0b[c][p], m);
                    h1b[c][p] += __shfl_xor(h1b[c][p], m);
                }
            }
        if (lane < 8) {
            #pragma unroll
            for (int c = 0; c < 3; ++c)
                #pragma unroll
                for (int p = 0; p < 3; ++p) {
                    red2[wv][lane][c*3 + p]     = h0b[c][p];
                    red2[wv][lane][9 + c*3 + p] = h1b[c][p];
                }
        }
    }
    __syncthreads();

    // ---- finalize: own (144 items) + halo (72 items), hw-cos prior ----
    if (tid < 144) {
        int gl = tid / 9, cp = tid - gl*9;
        int c = cp / 3, p = cp - c*3;
        float h0 = red[0][gl][cp]     + red[1][gl][cp]
                 + red[2][gl][cp]     + red[3][gl][cp];
        float h1 = red[0][gl][9 + cp] + red[1][gl][9 + cp]
                 + red[2][gl][9 + cp] + red[3][gl][9 + cp];
        float nh1 = h1 / (h0 + EPS);
        float xg = x_g[(b*NGG + g0 + gl)*3 + c];
        float fp = 0.f;
        #pragma unroll
        for (int k = 0; k < NBAS; ++k) {
            // arg bits match numpy (mul+add rn); hw cos of fract(arg/2pi):
            // reduction error <= ~0.012 rad at |arg|<=1.5e5 — inside threshold.
            float arg = __fadd_rn(__fmul_rn(sw_l[k*3 + p], xg), sb_l[k*3 + p]);
            float rev = arg * INV2PIF;
            rev = rev - floorf(rev);
            fp += rw_l[k] * COS_REV(rev);
        }
        fp *= 0.44721359549995793f;      // sqrt(2/10)
        int base = (b*NGG + g0 + gl)*9 + cp;
        out[H0_OFF  + base] = h0;
        out[NH1_OFF + base] = nh1;
        out[FP_OFF  + base] = fp;
        pre_l[cp][4 + gl] = nh1 + fp;
    } else if (tid < 216) {
        int it = tid - 144;
        int gh = it / 9, cp = it - gh*9;
        int c = cp / 3, p = cp - c*3;
        float h0 = red2[0][gh][cp]     + red2[1][gh][cp]
                 + red2[2][gh][cp]     + red2[3][gh][cp];
        float h1 = red2[0][gh][9 + cp] + red2[1][gh][9 + cp]
                 + red2[2][gh][9 + cp] + red2[3][gh][9 + cp];
        int gg  = g0 - 4 + ((gh < 4) ? gh : 20 + (gh - 4));
        int idx = (gh < 4) ? gh : 20 + (gh - 4);
        bool valid = (gg >= 0) && (gg < NGG);
        int ggc = min(max(gg, 0), NGG-1);
        float nh1 = h1 / (h0 + EPS);
        float xg = x_g[(b*NGG + ggc)*3 + c];
        float fp = 0.f;
        #pragma unroll
        for (int k = 0; k < NBAS; ++k) {
            float arg = __fadd_rn(__fmul_rn(sw_l[k*3 + p], xg), sb_l[k*3 + p]);
            float rev = arg * INV2PIF;
            rev = rev - floorf(rev);
            fp += rw_l[k] * COS_REV(rev);
        }
        fp *= 0.44721359549995793f;
        pre_l[cp][idx] = valid ? (nh1 + fp) : 0.f;   // zero-pad at grid edges
    }
    __syncthreads();

    // ---- depthwise conv (own 16 g) + deterministic BN partials ----
    float s1 = 0.f, s2 = 0.f;
    int cp2 = tid >> 4;            // valid when tid < 144
    if (tid < 144) {
        int gl = tid & 15;
        int c = cp2 / 3, p = cp2 - c*3;
        int K, pad; const float* w; float bias;
        if (p == 0)      { K = 3; pad = 1; w = cw1 + c*3; bias = cb1[c]; }
        else if (p == 1) { K = 5; pad = 2; w = cw2 + c*5; bias = cb2[c]; }
        else             { K = 9; pad = 4; w = cw3 + c*9; bias = cb3[c]; }
        float acc = bias;
        for (int k = 0; k < K; ++k)
            acc += w[k] * pre_l[cp2][4 + gl - pad + k];
        ws[WS_CONV + (b*9 + cp2)*NGG + g0 + gl] = acc;
        s1 = acc; s2 = acc*acc;
    }
    // reduce within each 16-lane group (same cp)
    #pragma unroll
    for (int m = 1; m <= 8; m <<= 1) {
        s1 += __shfl_xor(s1, m);
        s2 += __shfl_xor(s2, m);
    }
    if (tid < 144 && (tid & 15) == 0) {
        ws[WS_STATS + (cp2*512 + bid)*2]     = s1;
        ws[WS_STATS + (cp2*512 + bid)*2 + 1] = s2;
    }
}

// ---------------------------------------------------------------------------
// K2: BN stats reduce (512 partials/cp) + normalize (n_f) + output GEMV.
// 512 blocks x 256, each handling 16 P's.
// ---------------------------------------------------------------------------
__global__ __launch_bounds__(256) void k2_out(
    const float* __restrict__ bn_gamma, const float* __restrict__ bn_beta,
    const float* __restrict__ g_w, const float* __restrict__ g_b,
    float* __restrict__ out, float* __restrict__ ws)
{
    __shared__ float4 gw4[OUTC*18/4];     // float4-staged g_w
    __shared__ float feat_l[4][18];
    __shared__ float ps[9][16][2];
    __shared__ float mstat[9][2];
    const int tid = threadIdx.x;
    float* gw_l = (float*)gw4;

    for (int i = tid; i < OUTC*18/4; i += 256)
        gw4[i] = ((const float4*)g_w)[i];
    if (tid < 144) {
        int cp = tid / 16, q = tid & 15;
        float s1 = 0.f, s2 = 0.f;
        #pragma unroll 4
        for (int j = 0; j < 32; ++j) {
            int idx = WS_STATS + (cp*512 + q*32 + j)*2;
            s1 += ws[idx];
            s2 += ws[idx + 1];
        }
        ps[cp][q][0] = s1; ps[cp][q][1] = s2;
    }
    __syncthreads();
    if (tid < 9) {
        float s1 = 0.f, s2 = 0.f;
        #pragma unroll
        for (int q = 0; q < 16; ++q) { s1 += ps[tid][q][0]; s2 += ps[tid][q][1]; }
        float mean = s1 * (1.0f/8192.0f);
        float var  = s2 * (1.0f/8192.0f) - mean*mean;
        mstat[tid][0] = mean;
        mstat[tid][1] = rsqrtf(var + BN_EPSF);
    }
    __syncthreads();

    const int pt = tid >> 6, o = tid & 63;
    #pragma unroll
    for (int rep = 0; rep < 4; ++rep) {
        if (tid < 72) {
            int pt2 = tid / 18, j = tid - pt2*18;
            int P = blockIdx.x*16 + rep*4 + pt2;
            int b = P >> 11, g = P & 2047;
            float f;
            if (j < 9) {
                f = out[H0_OFF + (b*NGG + g)*9 + j];
            } else {
                int cp = j - 9; int c = cp / 3, p = cp - c*3;
                float x = ws[WS_CONV + (b*9 + cp)*NGG + g];
                float v = bn_gamma[p*3 + c] * (x - mstat[cp][0]) * mstat[cp][1]
                          + bn_beta[p*3 + c];
                out[NF_OFF + (b*NGG + g)*9 + cp] = v;
                f = v;
            }
            feat_l[pt2][j] = f;
        }
        __syncthreads();

        int P = blockIdx.x*16 + rep*4 + pt;
        int b = P >> 11, g = P & 2047;
        float acc = g_b[o];
        #pragma unroll
        for (int j = 0; j < 18; ++j) acc += feat_l[pt][j] * gw_l[o*18 + j];
        out[Y_OFF + (b*NGG + g)*OUTC + o] = acc;
        __syncthreads();
    }
}

extern "C" void kernel_launch(void* const* d_in, const int* in_sizes, int n_in,
                              void* d_out, int out_size, void* d_ws, size_t ws_size,
                              hipStream_t stream)
{
    const float* x_c      = (const float*)d_in[0];
    const float* y_c      = (const float*)d_in[1];
    const float* x_g      = (const float*)d_in[2];
    const float* sigma    = (const float*)d_in[3];
    const float* mu       = (const float*)d_in[4];
    const float* eps1     = (const float*)d_in[5];
    const float* b_u      = (const float*)d_in[6];
    const float* random_w = (const float*)d_in[7];
    const float* conv_w1  = (const float*)d_in[8];
    const float* conv_b1  = (const float*)d_in[9];
    const float* conv_w2  = (const float*)d_in[10];
    const float* conv_b2  = (const float*)d_in[11];
    const float* conv_w3  = (const float*)d_in[12];
    const float* conv_b3  = (const float*)d_in[13];
    const float* bn_gamma = (const float*)d_in[14];
    const float* bn_beta  = (const float*)d_in[15];
    const float* g_w      = (const float*)d_in[16];
    const float* g_b      = (const float*)d_in[17];

    float* outp = (float*)d_out;
    float* wsp  = (float*)d_ws;

    k1_fused<<<NBB*128, 256, 0, stream>>>(x_c, y_c, x_g, sigma, mu, eps1, b_u,
                                          random_w, conv_w1, conv_b1, conv_w2,
                                          conv_b2, conv_w3, conv_b3, outp, wsp);
    k2_out<<<(NBB*NGG)/16, 256, 0, stream>>>(bn_gamma, bn_beta, g_w, g_b, outp, wsp);
}

// Round 14
// 22.500 us; speedup vs baseline: 1.2506x; 1.2506x over previous
//
#include <hip/hip_runtime.h>
#include <math.h>

#define EPS 1e-6f
#define BN_EPSF 1e-5f
#define PI2F 6.2831853071795864769f
#define INV2PIF 0.15915494309189535f
#define LOG2EF 1.4426950408889634f
#define NBB 4
#define NCC 512
#define NGG 2048
#define OUTC 64
#define NBAS 10

// d_out layout (floats): y_out, n_f, fourier_prior, n_h1, h0_f
#define Y_OFF   0
#define NF_OFF  (NBB*NGG*OUTC)          // 524288
#define FP_OFF  (NF_OFF  + NBB*NGG*9)   // 598016
#define NH1_OFF (FP_OFF  + NBB*NGG*9)   // 671744
#define H0_OFF  (NH1_OFF + NBB*NGG*9)   // 745472

// ws layout (floats)
#define WSH0     0                      // raw h0 sums, NBB*9*NGG = 73728
#define WSH1     (NBB*9*NGG)            // raw h1 sums
#define WS_CONV  (2*NBB*9*NGG)          // conv outputs
#define WS_STATS (3*NBB*9*NGG)          // 9 cps * 32 blocks * {sum,sumsq}

#if defined(__has_builtin)
# if __has_builtin(__builtin_amdgcn_exp2f)
#  define EXP2F(x) __builtin_amdgcn_exp2f(x)
# endif
# if __has_builtin(__builtin_amdgcn_cosf)
#  define COS_REV(r) __builtin_amdgcn_cosf(r)   // cos(2*pi*r), r in [0,1)
# endif
#endif
#ifndef EXP2F
# define EXP2F(x) exp2f(x)
#endif
#ifndef COS_REV
# define COS_REV(r) cosf(PI2F*(r))
#endif

// ---------------------------------------------------------------------------
// K1: RBF partial sums, ONE CHANNEL per block. 1536 blocks
// (4 b x 128 tiles of 16 g x 3 c) x 256 threads.
//
// Round-14 thesis: every prior k1 was VGPR-capped (18 accs ~80 VGPR -> max
// 4 waves/SIMD, m69 halving at >64). Splitting c across blocks leaves only
// 6 live accumulators (~40 VGPR); __launch_bounds__(256,8) caps at 64 VGPR
// -> 8 blocks/CU = 32 waves/CU candidate occupancy, at ZERO extra exp work
// (37.7M total, same as minimum; round-8's p-outer paid 3x LDS reads).
// LDS: only this block's channel slice (4 KB), skewed n*2+(n>>5)*2 so the
// wave's 4 broadcast groups hit distinct banks with AFFINE addresses.
// ---------------------------------------------------------------------------
__global__ __launch_bounds__(256, 8) void k1_rbf(
    const float* __restrict__ x_c, const float* __restrict__ y_c,
    const float* __restrict__ x_g, const float* __restrict__ sigma,
    float* __restrict__ ws)
{
    const int bid = blockIdx.x;
    const int c   = bid % 3;           // channel owned by this block
    const int t   = bid / 3;           // 0..511
    const int b   = t >> 7;            // batch
    const int g0  = (t & 127) * 16;    // g-tile base
    const int tid = threadIdx.x;

    __shared__ float cxy[NCC*2 + (NCC/32)*2];  // 4.1 KB skewed (x,y) slice
    __shared__ float red[16][16][7];           // 7.2 KB chunk partials (+pad)

    // ---- stage this channel's context slice (stride-3 source) ----
    const float* xcb = x_c + b*NCC*3 + c;
    const float* ycb = y_c + b*NCC*3 + c;
    for (int n = tid; n < NCC; n += 256) {
        int base = n*2 + ((n>>5)<<1);
        cxy[base]     = xcb[n*3];
        cxy[base + 1] = ycb[n*3];
    }

    float coef[3];
    #pragma unroll
    for (int p = 0; p < 3; ++p) {
        float s = expf(sigma[p]) + EPS;
        coef[p] = (-0.5f * LOG2EF) / (s*s);   // exp(-0.5 d^2) == exp2(d^2*coef)
    }

    // mapping: g = tid&15, chunk cA = tid>>4 (16 chunks of 32 ctx)
    const int gA = tid & 15;
    const int cA = tid >> 4;
    const float xg = x_g[(b*NGG + g0 + gA)*3 + c];

    __syncthreads();

    // ---- RBF inner loop: 32 ctx/thread, 3 exp/iter, 6 live accumulators ----
    float h00 = 0.f, h01 = 0.f, h02 = 0.f;     // h0 for p=0,1,2
    float h10 = 0.f, h11 = 0.f, h12 = 0.f;     // h1 for p=0,1,2
    const int fbase = cA * 66;                 // 32 ctx * 2 + 2-float skew
    #pragma unroll 4
    for (int i = 0; i < 32; ++i) {
        float2 XY = *(const float2*)&cxy[fbase + i*2];
        float d  = XY.x - xg;
        float d2 = d * d;
        float w0 = EXP2F(d2 * coef[0]);
        float w1 = EXP2F(d2 * coef[1]);
        float w2 = EXP2F(d2 * coef[2]);
        h00 += w0; h10 += w0 * XY.y;
        h01 += w1; h11 += w1 * XY.y;
        h02 += w2; h12 += w2 * XY.y;
    }
    red[cA][gA][0] = h00;  red[cA][gA][1] = h01;  red[cA][gA][2] = h02;
    red[cA][gA][3] = h10;  red[cA][gA][4] = h11;  red[cA][gA][5] = h12;
    __syncthreads();

    // ---- reduce 16 chunks -> 96 outputs (16 g x {h0,h1} x 3 p) ----
    if (tid < 96) {
        int g = tid / 6, j = tid - g*6;
        float s = 0.f;
        #pragma unroll
        for (int q = 0; q < 16; ++q) s += red[q][g][j];
        int p = (j < 3) ? j : j - 3;
        int idx = (b*9 + c*3 + p)*NGG + g0 + g;
        ws[((j < 3) ? WSH0 : WSH1) + idx] = s;
    }
}

// ---------------------------------------------------------------------------
// K2: finalize (nh1 + Fourier prior via HW cos) for 256 own g + 8 halo g,
// then depthwise conv + BN partials. 288 blocks (4 b x 9 cp x 8 gc) x 256.
// (verbatim round-11, the 23.8 us run)
// ---------------------------------------------------------------------------
__global__ __launch_bounds__(256) void k2_fin_conv(
    const float* __restrict__ x_g, const float* __restrict__ sigma,
    const float* __restrict__ mu, const float* __restrict__ eps1,
    const float* __restrict__ b_u, const float* __restrict__ random_w,
    const float* __restrict__ cw1, const float* __restrict__ cb1,
    const float* __restrict__ cw2, const float* __restrict__ cb2,
    const float* __restrict__ cw3, const float* __restrict__ cb3,
    float* __restrict__ out, float* __restrict__ ws)
{
    const int bid = blockIdx.x;           // 4b x 9cp x 8gc = 288
    const int b = bid / 72; int r = bid - b*72;
    const int cp = r >> 3;  const int gc = r & 7;
    const int c = cp / 3, p = cp - c*3;
    const int tid = threadIdx.x;

    __shared__ float pre_l[264];          // 0..3 left halo, 4..259 own, 260..263 right
    __shared__ float swl[NBAS], sbl[NBAS], rwl[NBAS];
    __shared__ float r1[4], r2[4];

    if (tid < NBAS) {
        float wmu  = expf(mu[p]);
        float wstd = 1.0f / (expf(sigma[p]) + EPS);
        swl[tid] = wmu + wstd * eps1[(b*NBAS + tid)*3 + p];
        sbl[tid] = PI2F * b_u[(b*NBAS + tid)*3 + p];
        rwl[tid] = random_w[tid];
    }
    __syncthreads();

    for (int s = tid; s < 264; s += 256) {
        int gf = gc*256 - 4 + s;
        float v = 0.f;
        if (gf >= 0 && gf < NGG) {
            int idx = (b*9 + cp)*NGG + gf;
            float h0 = ws[WSH0 + idx];
            float h1 = ws[WSH1 + idx];
            float nh1 = h1 / (h0 + EPS);
            float xg = x_g[(b*NGG + gf)*3 + c];
            float fp = 0.f;
            #pragma unroll
            for (int k = 0; k < NBAS; ++k) {
                // arg bits match numpy (mul+add, round-to-nearest);
                // cos via HW: cos(arg) = v_cos(fract(arg/2pi)); reduction
                // error <= ~0.012 rad at |arg|<=1.5e5 — inside threshold.
                float arg = __fadd_rn(__fmul_rn(swl[k], xg), sbl[k]);
                float rev = arg * INV2PIF;
                rev = rev - floorf(rev);
                fp += rwl[k] * COS_REV(rev);
            }
            fp *= 0.44721359549995793f;   // sqrt(2/10)
            v = nh1 + fp;
            if (s >= 4 && s < 260) {      // own range: write the three outputs
                int obase = (b*NGG + gf)*9 + cp;
                out[H0_OFF  + obase] = h0;
                out[NH1_OFF + obase] = nh1;
                out[FP_OFF  + obase] = fp;
            }
        }
        pre_l[s] = v;                     // zero beyond grid edges (conv zero-pad)
    }
    __syncthreads();

    // depthwise conv (own 256 g) + deterministic BN partials
    int K, pad; const float* w; float bias;
    if (p == 0)      { K = 3; pad = 1; w = cw1 + c*3; bias = cb1[c]; }
    else if (p == 1) { K = 5; pad = 2; w = cw2 + c*5; bias = cb2[c]; }
    else             { K = 9; pad = 4; w = cw3 + c*9; bias = cb3[c]; }

    float acc = bias;
    for (int k = 0; k < K; ++k)
        acc += w[k] * pre_l[tid + 4 - pad + k];
    ws[WS_CONV + (b*9 + cp)*NGG + gc*256 + tid] = acc;

    float s1 = acc, s2 = acc*acc;
    #pragma unroll
    for (int o = 32; o > 0; o >>= 1) {
        s1 += __shfl_down(s1, o);
        s2 += __shfl_down(s2, o);
    }
    int lane = tid & 63, wv = tid >> 6;
    if (lane == 0) { r1[wv] = s1; r2[wv] = s2; }
    __syncthreads();
    if (tid == 0) {
        float t1 = r1[0] + r1[1] + r1[2] + r1[3];
        float t2 = r2[0] + r2[1] + r2[2] + r2[3];
        int pidx = cp*32 + b*8 + gc;
        ws[WS_STATS + pidx*2]     = t1;
        ws[WS_STATS + pidx*2 + 1] = t2;
    }
}

// ---------------------------------------------------------------------------
// K3: BN stats reduce + normalize (n_f) + output GEMV. 2048 blocks x 256.
// (verbatim round-11, the 23.8 us run)
// ---------------------------------------------------------------------------
__global__ __launch_bounds__(256) void k3_out(
    const float* __restrict__ bn_gamma, const float* __restrict__ bn_beta,
    const float* __restrict__ g_w, const float* __restrict__ g_b,
    float* __restrict__ out, float* __restrict__ ws)
{
    __shared__ float4 gw4[OUTC*18/4];     // float4-staged g_w
    __shared__ float feat_l[4][18];
    __shared__ float ps[9][16][2];
    __shared__ float mstat[9][2];
    const int tid = threadIdx.x;
    float* gw_l = (float*)gw4;

    for (int i = tid; i < OUTC*18/4; i += 256)
        gw4[i] = ((const float4*)g_w)[i];
    if (tid < 144) {
        int cp = tid / 16, q = tid & 15;
        int idx = WS_STATS + (cp*32 + 2*q)*2;
        ps[cp][q][0] = ws[idx]     + ws[idx + 2];
        ps[cp][q][1] = ws[idx + 1] + ws[idx + 3];
    }
    __syncthreads();
    if (tid < 9) {
        float s1 = 0.f, s2 = 0.f;
        #pragma unroll
        for (int q = 0; q < 16; ++q) { s1 += ps[tid][q][0]; s2 += ps[tid][q][1]; }
        float mean = s1 * (1.0f/8192.0f);
        float var  = s2 * (1.0f/8192.0f) - mean*mean;
        mstat[tid][0] = mean;
        mstat[tid][1] = rsqrtf(var + BN_EPSF);
    }
    __syncthreads();

    if (tid < 72) {
        int pt = tid / 18, j = tid - pt*18;
        int P = blockIdx.x*4 + pt;
        int b = P >> 11, g = P & 2047;
        float f;
        if (j < 9) {
            f = out[H0_OFF + (b*NGG + g)*9 + j];
        } else {
            int cp = j - 9; int c = cp / 3, p = cp - c*3;
            float x = ws[WS_CONV + (b*9 + cp)*NGG + g];
            float v = bn_gamma[p*3 + c] * (x - mstat[cp][0]) * mstat[cp][1]
                      + bn_beta[p*3 + c];
            out[NF_OFF + (b*NGG + g)*9 + cp] = v;
            f = v;
        }
        feat_l[pt][j] = f;
    }
    __syncthreads();

    int pt = tid >> 6, o = tid & 63;
    int P = blockIdx.x*4 + pt;
    int b = P >> 11, g = P & 2047;
    float acc = g_b[o];
    #pragma unroll
    for (int j = 0; j < 18; ++j) acc += feat_l[pt][j] * gw_l[o*18 + j];
    out[Y_OFF + (b*NGG + g)*OUTC + o] = acc;
}

extern "C" void kernel_launch(void* const* d_in, const int* in_sizes, int n_in,
                              void* d_out, int out_size, void* d_ws, size_t ws_size,
                              hipStream_t stream)
{
    const float* x_c      = (const float*)d_in[0];
    const float* y_c      = (const float*)d_in[1];
    const float* x_g      = (const float*)d_in[2];
    const float* sigma    = (const float*)d_in[3];
    const float* mu       = (const float*)d_in[4];
    const float* eps1     = (const float*)d_in[5];
    const float* b_u      = (const float*)d_in[6];
    const float* random_w = (const float*)d_in[7];
    const float* conv_w1  = (const float*)d_in[8];
    const float* conv_b1  = (const float*)d_in[9];
    const float* conv_w2  = (const float*)d_in[10];
    const float* conv_b2  = (const float*)d_in[11];
    const float* conv_w3  = (const float*)d_in[12];
    const float* conv_b3  = (const float*)d_in[13];
    const float* bn_gamma = (const float*)d_in[14];
    const float* bn_beta  = (const float*)d_in[15];
    const float* g_w      = (const float*)d_in[16];
    const float* g_b      = (const float*)d_in[17];

    float* outp = (float*)d_out;
    float* wsp  = (float*)d_ws;

    k1_rbf<<<NBB*128*3, 256, 0, stream>>>(x_c, y_c, x_g, sigma, wsp);
    k2_fin_conv<<<NBB*9*(NGG/256), 256, 0, stream>>>(x_g, sigma, mu, eps1, b_u,
                                                     random_w, conv_w1, conv_b1,
                                                     conv_w2, conv_b2, conv_w3,
                                                     conv_b3, outp, wsp);
    k3_out<<<(NBB*NGG)/4, 256, 0, stream>>>(bn_gamma, bn_beta, g_w, g_b, outp, wsp);
}

// Round 15
// 21.657 us; speedup vs baseline: 1.2993x; 1.0390x over previous
//
#include <hip/hip_runtime.h>
#include <math.h>

#define EPS 1e-6f
#define BN_EPSF 1e-5f
#define PI2F 6.2831853071795864769f
#define INV2PIF 0.15915494309189535f
#define LOG2EF 1.4426950408889634f
#define NBB 4
#define NCC 512
#define NGG 2048
#define OUTC 64
#define NBAS 10

// d_out layout (floats): y_out, n_f, fourier_prior, n_h1, h0_f
#define Y_OFF   0
#define NF_OFF  (NBB*NGG*OUTC)          // 524288
#define FP_OFF  (NF_OFF  + NBB*NGG*9)   // 598016
#define NH1_OFF (FP_OFF  + NBB*NGG*9)   // 671744
#define H0_OFF  (NH1_OFF + NBB*NGG*9)   // 745472

// ws layout (floats)
#define WSH01    0                      // interleaved (h0,h1) pairs, 2*73728
#define WS_CONV  (2*NBB*9*NGG)          // conv outputs
#define WS_STATS (3*NBB*9*NGG)          // 9 cps * 32 blocks * {sum,sumsq}

#if defined(__has_builtin)
# if __has_builtin(__builtin_amdgcn_exp2f)
#  define EXP2F(x) __builtin_amdgcn_exp2f(x)
# endif
# if __has_builtin(__builtin_amdgcn_cosf)
#  define COS_REV(r) __builtin_amdgcn_cosf(r)   // cos(2*pi*r), r in [0,1)
# endif
#endif
#ifndef EXP2F
# define EXP2F(x) exp2f(x)
#endif
#ifndef COS_REV
# define COS_REV(r) cosf(PI2F*(r))
#endif

// ---------------------------------------------------------------------------
// K1: RBF partial sums, ONE CHANNEL per block (r14 structure, best known).
// 1536 blocks (4 b x 128 tiles of 16 g x 3 c) x 256 threads, 6 accumulators
// (~45 VGPR), __launch_bounds__(256,8) -> 64-VGPR cap, 8 blocks/CU capacity.
// r15: unroll 8 (deeper ILP), pair-grouped accumulate (SLP -> v_pk_*),
// interleaved (h0,h1) output pairs for k2's coalesced float2 reads.
// ---------------------------------------------------------------------------
__global__ __launch_bounds__(256, 8) void k1_rbf(
    const float* __restrict__ x_c, const float* __restrict__ y_c,
    const float* __restrict__ x_g, const float* __restrict__ sigma,
    float* __restrict__ ws)
{
    const int bid = blockIdx.x;
    const int c   = bid % 3;           // channel owned by this block
    const int t   = bid / 3;           // 0..511
    const int b   = t >> 7;            // batch
    const int g0  = (t & 127) * 16;    // g-tile base
    const int tid = threadIdx.x;

    __shared__ float cxy[NCC*2 + (NCC/32)*2];  // 4.1 KB skewed (x,y) slice
    __shared__ float red[16][16][7];           // 7.2 KB chunk partials (+pad)

    // ---- stage this channel's context slice (stride-3 source) ----
    const float* xcb = x_c + b*NCC*3 + c;
    const float* ycb = y_c + b*NCC*3 + c;
    for (int n = tid; n < NCC; n += 256) {
        int base = n*2 + ((n>>5)<<1);
        cxy[base]     = xcb[n*3];
        cxy[base + 1] = ycb[n*3];
    }

    float coef[3];
    #pragma unroll
    for (int p = 0; p < 3; ++p) {
        float s = expf(sigma[p]) + EPS;
        coef[p] = (-0.5f * LOG2EF) / (s*s);   // exp(-0.5 d^2) == exp2(d^2*coef)
    }

    // mapping: g = tid&15, chunk cA = tid>>4 (16 chunks of 32 ctx)
    const int gA = tid & 15;
    const int cA = tid >> 4;
    const float xg = x_g[(b*NGG + g0 + gA)*3 + c];

    __syncthreads();

    // ---- RBF inner loop: 32 ctx/thread, 3 exp/iter, 6 live accumulators ----
    float h00 = 0.f, h01 = 0.f, h02 = 0.f;     // h0 for p=0,1,2
    float h10 = 0.f, h11 = 0.f, h12 = 0.f;     // h1 for p=0,1,2
    const int fbase = cA * 66;                 // 32 ctx * 2 + 2-float skew
    #pragma unroll 8
    for (int i = 0; i < 32; ++i) {
        float2 XY = *(const float2*)&cxy[fbase + i*2];
        float d  = XY.x - xg;
        float d2 = d * d;
        // pair-grouped so the SLP vectorizer can emit v_pk_mul/add/fma
        float t0 = d2 * coef[0];
        float t1 = d2 * coef[1];
        float t2 = d2 * coef[2];
        float w0 = EXP2F(t0);
        float w1 = EXP2F(t1);
        float w2 = EXP2F(t2);
        h00 += w0;  h01 += w1;
        h02 += w2;
        h10 = fmaf(w0, XY.y, h10);  h11 = fmaf(w1, XY.y, h11);
        h12 = fmaf(w2, XY.y, h12);
    }
    red[cA][gA][0] = h00;  red[cA][gA][1] = h01;  red[cA][gA][2] = h02;
    red[cA][gA][3] = h10;  red[cA][gA][4] = h11;  red[cA][gA][5] = h12;
    __syncthreads();

    // ---- reduce 16 chunks -> 96 outputs (16 g x {h0,h1} x 3 p), pairs ----
    if (tid < 96) {
        int g = tid / 6, j = tid - g*6;
        float s = 0.f;
        #pragma unroll
        for (int q = 0; q < 16; ++q) s += red[q][g][j];
        int p = (j < 3) ? j : j - 3;
        int idx = (b*9 + c*3 + p)*NGG + g0 + g;
        ws[WSH01 + idx*2 + ((j < 3) ? 0 : 1)] = s;   // interleaved (h0,h1)
    }
}

// ---------------------------------------------------------------------------
// K2: finalize (nh1 + Fourier prior via HW cos) for 256 own g + 8 halo g,
// then depthwise conv + BN partials. 288 blocks (4 b x 9 cp x 8 gc) x 256.
// r15: single coalesced float2 read of the (h0,h1) pair per item.
// ---------------------------------------------------------------------------
__global__ __launch_bounds__(256) void k2_fin_conv(
    const float* __restrict__ x_g, const float* __restrict__ sigma,
    const float* __restrict__ mu, const float* __restrict__ eps1,
    const float* __restrict__ b_u, const float* __restrict__ random_w,
    const float* __restrict__ cw1, const float* __restrict__ cb1,
    const float* __restrict__ cw2, const float* __restrict__ cb2,
    const float* __restrict__ cw3, const float* __restrict__ cb3,
    float* __restrict__ out, float* __restrict__ ws)
{
    const int bid = blockIdx.x;           // 4b x 9cp x 8gc = 288
    const int b = bid / 72; int r = bid - b*72;
    const int cp = r >> 3;  const int gc = r & 7;
    const int c = cp / 3, p = cp - c*3;
    const int tid = threadIdx.x;

    __shared__ float pre_l[264];          // 0..3 left halo, 4..259 own, 260..263 right
    __shared__ float swl[NBAS], sbl[NBAS], rwl[NBAS];
    __shared__ float r1[4], r2[4];

    if (tid < NBAS) {
        float wmu  = expf(mu[p]);
        float wstd = 1.0f / (expf(sigma[p]) + EPS);
        swl[tid] = wmu + wstd * eps1[(b*NBAS + tid)*3 + p];
        sbl[tid] = PI2F * b_u[(b*NBAS + tid)*3 + p];
        rwl[tid] = random_w[tid];
    }
    __syncthreads();

    for (int s = tid; s < 264; s += 256) {
        int gf = gc*256 - 4 + s;
        float v = 0.f;
        if (gf >= 0 && gf < NGG) {
            int idx = (b*9 + cp)*NGG + gf;
            float2 hv = *(const float2*)&ws[WSH01 + idx*2];
            float h0 = hv.x;
            float h1 = hv.y;
            float nh1 = h1 / (h0 + EPS);
            float xg = x_g[(b*NGG + gf)*3 + c];
            float fp = 0.f;
            #pragma unroll
            for (int k = 0; k < NBAS; ++k) {
                // arg bits match numpy (mul+add, round-to-nearest);
                // cos via HW: cos(arg) = v_cos(fract(arg/2pi)); reduction
                // error <= ~0.012 rad at |arg|<=1.5e5 — inside threshold.
                float arg = __fadd_rn(__fmul_rn(swl[k], xg), sbl[k]);
                float rev = arg * INV2PIF;
                rev = rev - floorf(rev);
                fp += rwl[k] * COS_REV(rev);
            }
            fp *= 0.44721359549995793f;   // sqrt(2/10)
            v = nh1 + fp;
            if (s >= 4 && s < 260) {      // own range: write the three outputs
                int obase = (b*NGG + gf)*9 + cp;
                out[H0_OFF  + obase] = h0;
                out[NH1_OFF + obase] = nh1;
                out[FP_OFF  + obase] = fp;
            }
        }
        pre_l[s] = v;                     // zero beyond grid edges (conv zero-pad)
    }
    __syncthreads();

    // depthwise conv (own 256 g) + deterministic BN partials
    int K, pad; const float* w; float bias;
    if (p == 0)      { K = 3; pad = 1; w = cw1 + c*3; bias = cb1[c]; }
    else if (p == 1) { K = 5; pad = 2; w = cw2 + c*5; bias = cb2[c]; }
    else             { K = 9; pad = 4; w = cw3 + c*9; bias = cb3[c]; }

    float acc = bias;
    for (int k = 0; k < K; ++k)
        acc += w[k] * pre_l[tid + 4 - pad + k];
    ws[WS_CONV + (b*9 + cp)*NGG + gc*256 + tid] = acc;

    float s1 = acc, s2 = acc*acc;
    #pragma unroll
    for (int o = 32; o > 0; o >>= 1) {
        s1 += __shfl_down(s1, o);
        s2 += __shfl_down(s2, o);
    }
    int lane = tid & 63, wv = tid >> 6;
    if (lane == 0) { r1[wv] = s1; r2[wv] = s2; }
    __syncthreads();
    if (tid == 0) {
        float t1 = r1[0] + r1[1] + r1[2] + r1[3];
        float t2 = r2[0] + r2[1] + r2[2] + r2[3];
        int pidx = cp*32 + b*8 + gc;
        ws[WS_STATS + pidx*2]     = t1;
        ws[WS_STATS + pidx*2 + 1] = t2;
    }
}

// ---------------------------------------------------------------------------
// K3: BN stats reduce + normalize (n_f) + output GEMV. 2048 blocks x 256.
// (verbatim r14)
// ---------------------------------------------------------------------------
__global__ __launch_bounds__(256) void k3_out(
    const float* __restrict__ bn_gamma, const float* __restrict__ bn_beta,
    const float* __restrict__ g_w, const float* __restrict__ g_b,
    float* __restrict__ out, float* __restrict__ ws)
{
    __shared__ float4 gw4[OUTC*18/4];     // float4-staged g_w
    __shared__ float feat_l[4][18];
    __shared__ float ps[9][16][2];
    __shared__ float mstat[9][2];
    const int tid = threadIdx.x;
    float* gw_l = (float*)gw4;

    for (int i = tid; i < OUTC*18/4; i += 256)
        gw4[i] = ((const float4*)g_w)[i];
    if (tid < 144) {
        int cp = tid / 16, q = tid & 15;
        int idx = WS_STATS + (cp*32 + 2*q)*2;
        ps[cp][q][0] = ws[idx]     + ws[idx + 2];
        ps[cp][q][1] = ws[idx + 1] + ws[idx + 3];
    }
    __syncthreads();
    if (tid < 9) {
        float s1 = 0.f, s2 = 0.f;
        #pragma unroll
        for (int q = 0; q < 16; ++q) { s1 += ps[tid][q][0]; s2 += ps[tid][q][1]; }
        float mean = s1 * (1.0f/8192.0f);
        float var  = s2 * (1.0f/8192.0f) - mean*mean;
        mstat[tid][0] = mean;
        mstat[tid][1] = rsqrtf(var + BN_EPSF);
    }
    __syncthreads();

    if (tid < 72) {
        int pt = tid / 18, j = tid - pt*18;
        int P = blockIdx.x*4 + pt;
        int b = P >> 11, g = P & 2047;
        float f;
        if (j < 9) {
            f = out[H0_OFF + (b*NGG + g)*9 + j];
        } else {
            int cp = j - 9; int c = cp / 3, p = cp - c*3;
            float x = ws[WS_CONV + (b*9 + cp)*NGG + g];
            float v = bn_gamma[p*3 + c] * (x - mstat[cp][0]) * mstat[cp][1]
                      + bn_beta[p*3 + c];
            out[NF_OFF + (b*NGG + g)*9 + cp] = v;
            f = v;
        }
        feat_l[pt][j] = f;
    }
    __syncthreads();

    int pt = tid >> 6, o = tid & 63;
    int P = blockIdx.x*4 + pt;
    int b = P >> 11, g = P & 2047;
    float acc = g_b[o];
    #pragma unroll
    for (int j = 0; j < 18; ++j) acc += feat_l[pt][j] * gw_l[o*18 + j];
    out[Y_OFF + (b*NGG + g)*OUTC + o] = acc;
}

extern "C" void kernel_launch(void* const* d_in, const int* in_sizes, int n_in,
                              void* d_out, int out_size, void* d_ws, size_t ws_size,
                              hipStream_t stream)
{
    const float* x_c      = (const float*)d_in[0];
    const float* y_c      = (const float*)d_in[1];
    const float* x_g      = (const float*)d_in[2];
    const float* sigma    = (const float*)d_in[3];
    const float* mu       = (const float*)d_in[4];
    const float* eps1     = (const float*)d_in[5];
    const float* b_u      = (const float*)d_in[6];
    const float* random_w = (const float*)d_in[7];
    const float* conv_w1  = (const float*)d_in[8];
    const float* conv_b1  = (const float*)d_in[9];
    const float* conv_w2  = (const float*)d_in[10];
    const float* conv_b2  = (const float*)d_in[11];
    const float* conv_w3  = (const float*)d_in[12];
    const float* conv_b3  = (const float*)d_in[13];
    const float* bn_gamma = (const float*)d_in[14];
    const float* bn_beta  = (const float*)d_in[15];
    const float* g_w      = (const float*)d_in[16];
    const float* g_b      = (const float*)d_in[17];

    float* outp = (float*)d_out;
    float* wsp  = (float*)d_ws;

    k1_rbf<<<NBB*128*3, 256, 0, stream>>>(x_c, y_c, x_g, sigma, wsp);
    k2_fin_conv<<<NBB*9*(NGG/256), 256, 0, stream>>>(x_g, sigma, mu, eps1, b_u,
                                                     random_w, conv_w1, conv_b1,
                                                     conv_w2, conv_b2, conv_w3,
                                                     conv_b3, outp, wsp);
    k3_out<<<(NBB*NGG)/4, 256, 0, stream>>>(bn_gamma, bn_beta, g_w, g_b, outp, wsp);
}